// Round 7
// baseline (89.755 us; speedup 1.0000x reference)
//
#include <hip/hip_runtime.h>

#define NXS   65536
#define HID   32
#define BT    256            // 4 waves per block
#define NB    256            // 1024 waves total = 1/SIMD on 256 CUs
#define CC    4              // cells per lane
#define WHOLD 256            // cells held per wave
#define WOWN  64             // cells owned per wave
#define WHALO ((WHOLD - WOWN) / 2)   // 96 -> launches of <=96 steps
#define LUT_N 4096
#define LUT_INV  512.0f      // entries per unit c, range [-4,4)
#define LUT_BIAS 2048.0f

__device__ __forceinline__ float fexp2(float x) { return __builtin_amdgcn_exp2f(x); }
__device__ __forceinline__ float frcp(float x)  { return __builtin_amdgcn_rcpf(x); }
__device__ __forceinline__ float flog2(float x) { return __builtin_amdgcn_logf(x); }

__device__ __forceinline__ float fast_tanh(float x) {
    x = fminf(fmaxf(x, -15.0f), 15.0f);
    float e = fexp2(x * 2.8853900817779268f);   // e^{2x}
    return (e - 1.0f) * frcp(e + 1.0f);
}
__device__ __forceinline__ float fast_sigmoid(float x) {
    float e = fexp2(x * -1.4426950408889634f);
    return frcp(1.0f + e);
}

struct FinnPtrs {
    const float* tvec;
    const float* Dp;  const float* stencil; const float* BCp; const float* fp;
    const float* kdp; const float* betap;   const float* alphap; const float* rhosp;
    const float* nep; const float* vep;     const float* dxp;
};

// ---- Kernel 1: tabulate ret(c) = sigmoid(MLP(c)) * ret_fac on [-4,4) ----
__global__ __launch_bounds__(256) void finn_lut(
    const float* __restrict__ W0, const float* __restrict__ b0,
    const float* __restrict__ W1, const float* __restrict__ b1,
    const float* __restrict__ W2, const float* __restrict__ b2,
    const float* __restrict__ W3, const float* __restrict__ b3,
    const float* __restrict__ ret_fac, float* __restrict__ lut)
{
    const int i = blockIdx.x * 256 + threadIdx.x;
    if (i >= LUT_N) return;
    const float c = -4.0f + (float)i * (1.0f / LUT_INV);

    float h[HID], a[HID];
    #pragma unroll
    for (int j = 0; j < HID; ++j)
        h[j] = fast_tanh(fmaf(c, W0[j], b0[j]));

    #pragma unroll
    for (int j = 0; j < HID; ++j) a[j] = b1[j];
    #pragma unroll
    for (int k = 0; k < HID; ++k) {
        const float hk = h[k];
        #pragma unroll
        for (int j = 0; j < HID; ++j) a[j] = fmaf(hk, W1[k * HID + j], a[j]);
    }
    #pragma unroll
    for (int j = 0; j < HID; ++j) h[j] = fast_tanh(a[j]);

    #pragma unroll
    for (int j = 0; j < HID; ++j) a[j] = b2[j];
    #pragma unroll
    for (int k = 0; k < HID; ++k) {
        const float hk = h[k];
        #pragma unroll
        for (int j = 0; j < HID; ++j) a[j] = fmaf(hk, W2[k * HID + j], a[j]);
    }
    #pragma unroll
    for (int j = 0; j < HID; ++j) h[j] = fast_tanh(a[j]);

    float pre = b3[0];
    #pragma unroll
    for (int k = 0; k < HID; ++k) pre = fmaf(h[k], W3[k], pre);

    lut[i] = fast_sigmoid(pre) * ret_fac[0];
}

// ---- Kernel 2: wave-autonomous trapezoid, 4 cells/lane, NO barriers in loop ----
__global__ __launch_bounds__(BT) void finn_sweep(
    const float* __restrict__ uin, float* __restrict__ out,
    const float* __restrict__ lut_g, FinnPtrs P, int t0, int h)
{
    __shared__ float2 slut[LUT_N];   // (ret_i, ret_{i+1}), 32 KB

    const int tid = threadIdx.x;

    // stage paired LUT: 16 entries/thread
    #pragma unroll
    for (int j = 0; j < LUT_N / BT; ++j) {
        const int i = tid + j * BT;
        const float r0 = lut_g[i];
        const float r1 = lut_g[(i + 1 < LUT_N) ? (i + 1) : i];
        slut[i] = make_float2(r0, r1);
    }

    // wave-uniform scalars
    const float dt   = P.tvec[1] - P.tvec[0];
    const float s0   = P.stencil[0];
    const float s1   = P.stencil[1];
    const float dx   = P.dxp[0];
    const float A    = P.Dp[0] / (dx * dx);
    const float B    = P.vep[0] / dx;
    const float BC   = P.BCp[0];
    const float beta = P.betap[0];
    const float alp  = P.alphap[0];
    const float akd  = (1.0f - P.fp[0]) * P.kdp[0];
    const float rsne = P.rhosp[0] / P.nep[0];

    const float G    = dt * rsne * alp;
    const float GAKD = G * akd;
    const float S1c  = 1.0f - dt * alp;
    const float S2c  = dt * alp * akd;

    // uniform interior folded constants
    const float K1u = dt * (2.0f * A * s0 - B);
    const float K2u = dt * (A * s1 + B);
    const float K3u = dt * A * s1;

    // geometry: wave wg owns [wg*WOWN, wg*WOWN+WOWN), holds [base, base+WHOLD)
    const int wg   = blockIdx.x * 4 + (tid >> 6);
    const int lane = tid & 63;
    const int wOwn = wg * WOWN;
    int base = wOwn - WHALO;
    if (base < 0) base = 0;
    if (base > NXS - WHOLD) base = NXS - WHOLD;
    const int gi0 = base + lane * CC;
    const bool ownm = (gi0 >= wOwn) && (gi0 < wOwn + WOWN);   // all 4 or none

    // per-lane K overrides for the two global-boundary cells
    float K0_0 = 0.0f, K1_0 = K1u, K2_0 = K2u;       // cell 0 (left nbr coef)
    float K1_3 = K1u, K3_3 = K3u;                    // cell 3 (right nbr coef)
    if (gi0 == 0) {            // global cell 0: doubled left flux, cl = BC
        K0_0 = dt * BC * (2.0f * A * s1 + B);
        K1_0 = dt * (3.0f * A * s0 - B);
        K2_0 = 0.0f;
    }
    if (gi0 + 3 == NXS - 1) {  // global last cell: cr = c
        K1_3 = dt * (2.0f * A * s0 - B + A * s1);
        K3_3 = 0.0f;
    }

    // load 4 cells (2 float4)
    float c0, c1, c2, c3, sk0, sk1, sk2, sk3;
    {
        const float4* u4 = reinterpret_cast<const float4*>(uin);
        const float4 a01 = u4[gi0 / 2];
        const float4 a23 = u4[gi0 / 2 + 1];
        c0 = a01.x; sk0 = a01.y; c1 = a01.z; sk1 = a01.w;
        c2 = a23.x; sk2 = a23.y; c3 = a23.z; sk3 = a23.w;
    }

    __syncthreads();   // LUT visible to all 4 waves

    // prologue gathers for step 0
    float fr0, fr1, fr2, fr3;
    float2 L0, L1, L2, L3;
    {
        float tt;
        tt = fmaf(c0, LUT_INV, LUT_BIAS); tt = fminf(fmaxf(tt, 0.0f), 4094.9f);
        int i0 = (int)tt; fr0 = tt - (float)i0; L0 = slut[i0];
        tt = fmaf(c1, LUT_INV, LUT_BIAS); tt = fminf(fmaxf(tt, 0.0f), 4094.9f);
        int i1 = (int)tt; fr1 = tt - (float)i1; L1 = slut[i1];
        tt = fmaf(c2, LUT_INV, LUT_BIAS); tt = fminf(fmaxf(tt, 0.0f), 4094.9f);
        int i2 = (int)tt; fr2 = tt - (float)i2; L2 = slut[i2];
        tt = fmaf(c3, LUT_INV, LUT_BIAS); tt = fminf(fmaxf(tt, 0.0f), 4094.9f);
        int i3 = (int)tt; fr3 = tt - (float)i3; L3 = slut[i3];
    }

    float* __restrict__ orow = out + (size_t)t0 * NXS * 2 + 2 * gi0;

    for (int s = 0; s < h; ++s) {
        // neighbors across lanes (old values)
        const float clS = __shfl_up(c3, 1);     // left nbr of cell 0
        const float crS = __shfl_down(c0, 1);   // right nbr of cell 3

        // c^beta (exact) + ret (lerp)
        const float pw0 = fexp2(beta * flog2(fmaxf(c0, 1e-9f)));
        const float pw1 = fexp2(beta * flog2(fmaxf(c1, 1e-9f)));
        const float pw2 = fexp2(beta * flog2(fmaxf(c2, 1e-9f)));
        const float pw3 = fexp2(beta * flog2(fmaxf(c3, 1e-9f)));
        const float ret0 = fmaf(fr0, L0.y - L0.x, L0.x);
        const float ret1 = fmaf(fr1, L1.y - L1.x, L1.x);
        const float ret2 = fmaf(fr2, L2.y - L2.x, L2.x);
        const float ret3 = fmaf(fr3, L3.y - L3.x, L3.x);

        const float nsk0 = fmaf(S1c, sk0, S2c * pw0);
        const float nsk1 = fmaf(S1c, sk1, S2c * pw1);
        const float nsk2 = fmaf(S1c, sk2, S2c * pw2);
        const float nsk3 = fmaf(S1c, sk3, S2c * pw3);

        float t0_ = fmaf(K1_0, c0, K0_0); t0_ = fmaf(K2_0, clS, t0_); t0_ = fmaf(K3u, c1, t0_);
        float t1_ = K1u * c1;             t1_ = fmaf(K2u, c0, t1_);   t1_ = fmaf(K3u, c2, t1_);
        float t2_ = K1u * c2;             t2_ = fmaf(K2u, c1, t2_);   t2_ = fmaf(K3u, c3, t2_);
        float t3_ = K1_3 * c3;            t3_ = fmaf(K2u, c2, t3_);   t3_ = fmaf(K3_3, crS, t3_);

        float nc0 = fmaf(ret0, t0_, c0); nc0 = fmaf(-GAKD, pw0, nc0); nc0 = fmaf(G, sk0, nc0);
        float nc1 = fmaf(ret1, t1_, c1); nc1 = fmaf(-GAKD, pw1, nc1); nc1 = fmaf(G, sk1, nc1);
        float nc2 = fmaf(ret2, t2_, c2); nc2 = fmaf(-GAKD, pw2, nc2); nc2 = fmaf(G, sk2, nc2);
        float nc3 = fmaf(ret3, t3_, c3); nc3 = fmaf(-GAKD, pw3, nc3); nc3 = fmaf(G, sk3, nc3);

        c0 = nc0; c1 = nc1; c2 = nc2; c3 = nc3;
        sk0 = nsk0; sk1 = nsk1; sk2 = nsk2; sk3 = nsk3;

        // issue next-step gathers early (latency hides under store + next VALU)
        {
            float tt;
            tt = fmaf(c0, LUT_INV, LUT_BIAS); tt = fminf(fmaxf(tt, 0.0f), 4094.9f);
            int i0 = (int)tt; fr0 = tt - (float)i0; L0 = slut[i0];
            tt = fmaf(c1, LUT_INV, LUT_BIAS); tt = fminf(fmaxf(tt, 0.0f), 4094.9f);
            int i1 = (int)tt; fr1 = tt - (float)i1; L1 = slut[i1];
            tt = fmaf(c2, LUT_INV, LUT_BIAS); tt = fminf(fmaxf(tt, 0.0f), 4094.9f);
            int i2 = (int)tt; fr2 = tt - (float)i2; L2 = slut[i2];
            tt = fmaf(c3, LUT_INV, LUT_BIAS); tt = fminf(fmaxf(tt, 0.0f), 4094.9f);
            int i3 = (int)tt; fr3 = tt - (float)i3; L3 = slut[i3];
        }

        if (ownm) {
            float4* o4 = reinterpret_cast<float4*>(orow);
            o4[0] = make_float4(c0, sk0, c1, sk1);
            o4[1] = make_float4(c2, sk2, c3, sk3);
        }
        orow += NXS * 2;
    }
}

extern "C" void kernel_launch(void* const* d_in, const int* in_sizes, int n_in,
                              void* d_out, int out_size, void* d_ws, size_t ws_size,
                              hipStream_t stream)
{
    const float* u0 = (const float*)d_in[0];
    FinnPtrs P;
    P.tvec    = (const float*)d_in[1];
    const float* W0      = (const float*)d_in[2];
    const float* b0      = (const float*)d_in[3];
    const float* W1      = (const float*)d_in[4];
    const float* b1      = (const float*)d_in[5];
    const float* W2      = (const float*)d_in[6];
    const float* b2      = (const float*)d_in[7];
    const float* W3      = (const float*)d_in[8];
    const float* b3      = (const float*)d_in[9];
    const float* ret_fac = (const float*)d_in[10];
    P.Dp      = (const float*)d_in[11];
    P.stencil = (const float*)d_in[12];
    P.BCp     = (const float*)d_in[13];
    P.fp      = (const float*)d_in[14];
    P.kdp     = (const float*)d_in[15];
    P.betap   = (const float*)d_in[16];
    P.alphap  = (const float*)d_in[17];
    P.rhosp   = (const float*)d_in[18];
    P.nep     = (const float*)d_in[19];
    P.vep     = (const float*)d_in[20];
    P.dxp     = (const float*)d_in[21];

    float* out = (float*)d_out;
    float* lut = (float*)d_ws;          // 16 KB scratch
    const int T = in_sizes[1];          // 200

    hipLaunchKernelGGL(finn_lut, dim3(LUT_N / 256), dim3(256), 0, stream,
                       W0, b0, W1, b1, W2, b2, W3, b3, ret_fac, lut);

    int done = 0;
    while (done < T) {
        const int h = (T - done < WHALO) ? (T - done) : WHALO;   // 96, 96, 8
        const float* src = (done == 0) ? u0 : out + (size_t)(done - 1) * NXS * 2;
        hipLaunchKernelGGL(finn_sweep, dim3(NB), dim3(BT), 0, stream,
                           src, out, lut, P, done, h);
        done += h;
    }
}

// Round 8
// 87.894 us; speedup vs baseline: 1.0212x; 1.0212x over previous
//
#include <hip/hip_runtime.h>

#define NXS    65536
#define HID    32
#define BTL    512           // 8 waves per block
#define NB     256           // blocks (= CUs); 2048 waves = 2/SIMD
#define OWNB   256           // cells owned (output) per block
#define SSPAN  668           // cells spanned per block
#define MARG   206           // (SSPAN - OWNB) / 2
#define CC     3             // cells per lane; wave slab = 192 cells
#define EPOCH  62            // steps between refills (slab halo 62/side)
#define LUT_N  4096
#define LUT_INV  512.0f      // entries per unit c, range [-4,4)
#define LUT_BIAS 2048.0f

__device__ __forceinline__ float fexp2(float x) { return __builtin_amdgcn_exp2f(x); }
__device__ __forceinline__ float frcp(float x)  { return __builtin_amdgcn_rcpf(x); }
__device__ __forceinline__ float flog2(float x) { return __builtin_amdgcn_logf(x); }

__device__ __forceinline__ float fast_tanh(float x) {
    x = fminf(fmaxf(x, -15.0f), 15.0f);
    float e = fexp2(x * 2.8853900817779268f);   // e^{2x}
    return (e - 1.0f) * frcp(e + 1.0f);
}
__device__ __forceinline__ float fast_sigmoid(float x) {
    float e = fexp2(x * -1.4426950408889634f);
    return frcp(1.0f + e);
}

struct FinnPtrs {
    const float* tvec;
    const float* Dp;  const float* stencil; const float* BCp; const float* fp;
    const float* kdp; const float* betap;   const float* alphap; const float* rhosp;
    const float* nep; const float* vep;     const float* dxp;
};

// ---- Kernel 1: tabulate ret(c) on [-4, 4], LUT_N+1 entries (for slopes) ----
__global__ __launch_bounds__(256) void finn_lut(
    const float* __restrict__ W0, const float* __restrict__ b0,
    const float* __restrict__ W1, const float* __restrict__ b1,
    const float* __restrict__ W2, const float* __restrict__ b2,
    const float* __restrict__ W3, const float* __restrict__ b3,
    const float* __restrict__ ret_fac, float* __restrict__ lut)
{
    const int i = blockIdx.x * 256 + threadIdx.x;
    if (i > LUT_N) return;                       // LUT_N+1 entries
    const float c = -4.0f + (float)i * (1.0f / LUT_INV);

    float h[HID], a[HID];
    #pragma unroll
    for (int j = 0; j < HID; ++j)
        h[j] = fast_tanh(fmaf(c, W0[j], b0[j]));

    #pragma unroll
    for (int j = 0; j < HID; ++j) a[j] = b1[j];
    #pragma unroll
    for (int k = 0; k < HID; ++k) {
        const float hk = h[k];
        #pragma unroll
        for (int j = 0; j < HID; ++j) a[j] = fmaf(hk, W1[k * HID + j], a[j]);
    }
    #pragma unroll
    for (int j = 0; j < HID; ++j) h[j] = fast_tanh(a[j]);

    #pragma unroll
    for (int j = 0; j < HID; ++j) a[j] = b2[j];
    #pragma unroll
    for (int k = 0; k < HID; ++k) {
        const float hk = h[k];
        #pragma unroll
        for (int j = 0; j < HID; ++j) a[j] = fmaf(hk, W2[k * HID + j], a[j]);
    }
    #pragma unroll
    for (int j = 0; j < HID; ++j) h[j] = fast_tanh(a[j]);

    float pre = b3[0];
    #pragma unroll
    for (int k = 0; k < HID; ++k) pre = fmaf(h[k], W3[k], pre);

    lut[i] = fast_sigmoid(pre) * ret_fac[0];
}

// ---- Kernel 2: epoch-refill sweep. Waves autonomous for EPOCH steps,
//      LDS re-tile at refills. Single launch for T <= MARG steps. ----
__global__ __launch_bounds__(BTL) void finn_sweep(
    const float* __restrict__ uin, float* __restrict__ out,
    const float* __restrict__ lut_g, FinnPtrs P, int T)
{
    __shared__ float2 slut[LUT_N];    // (slope_i, icpt_i), 32 KB
    __shared__ float2 xbuf[SSPAN];    // refill exchange, 5.3 KB

    const int tid  = threadIdx.x;
    const int w    = tid >> 6;
    const int lane = tid & 63;

    // build slope/intercept LUT: ret(tt) = fmaf(tt, slope, icpt)
    for (int i = tid; i < LUT_N; i += BTL) {
        const float r0 = lut_g[i], r1 = lut_g[i + 1];
        const float sl = r1 - r0;
        slut[i] = make_float2(sl, fmaf(-(float)i, sl, r0));
    }

    // wave-uniform scalars
    const float dt   = P.tvec[1] - P.tvec[0];
    const float s0   = P.stencil[0];
    const float s1   = P.stencil[1];
    const float dx   = P.dxp[0];
    const float A    = P.Dp[0] / (dx * dx);
    const float B    = P.vep[0] / dx;
    const float BC   = P.BCp[0];
    const float beta = P.betap[0];
    const float alp  = P.alphap[0];
    const float akd  = (1.0f - P.fp[0]) * P.kdp[0];
    const float rsne = P.rhosp[0] / P.nep[0];

    const float G    = dt * rsne * alp;
    const float GAKD = G * akd;
    const float S1c  = 1.0f - dt * alp;
    const float S2c  = dt * alp * akd;
    const float K1u  = dt * (2.0f * A * s0 - B);
    const float K2u  = dt * (A * s1 + B);
    const float K3u  = dt * A * s1;

    const int b = blockIdx.x;
    int blockBase = b * OWNB - MARG;
    if (blockBase < 0) blockBase = 0;
    if (blockBase > NXS - SSPAN) blockBase = NXS - SSPAN;
    const bool leftA  = (blockBase == 0);
    const bool rightA = (blockBase == NXS - SSPAN);
    const int ownRelL = b * OWNB - blockBase;
    const int ownRelR = ownRelL + OWNB;

    // epoch-0 slab base (valid window = [0, SSPAN))
    int a = ((SSPAN - 192) * w) / 7;

    float c[CC], sk[CC];
    {
        const float2* __restrict__ in2 = reinterpret_cast<const float2*>(uin);
        #pragma unroll
        for (int j = 0; j < CC; ++j) {
            const float2 u = in2[blockBase + a + lane * CC + j];
            c[j] = u.x; sk[j] = u.y;
        }
    }
    __syncthreads();   // slut ready

    char* __restrict__ outc = reinterpret_cast<char*>(out);
    int done = 0;
    while (done < T) {
        int nst = T - done; if (nst > EPOCH) nst = EPOCH;

        // ---- per-epoch setup ----
        const int vL = leftA ? 0 : done;
        const int vR = rightA ? SSPAN : SSPAN - done;
        const int pd = vR - vL - 192;
        const int aPrev = vL + (pd * (w - 1)) / 7;
        const int aNext = vL + (pd * (w + 1)) / 7;
        int bLo = (w == 0) ? 0     : ((aPrev + 192 + a) >> 1);
        int bHi = (w == 7) ? SSPAN : ((a + 192 + aNext) >> 1);
        if (bLo < ownRelL) bLo = ownRelL;
        if (bHi > ownRelR) bHi = ownRelR;

        float K0[CC], K1[CC], K2[CC], K3[CC];
        bool st[CC];
        #pragma unroll
        for (int j = 0; j < CC; ++j) {
            const int si = a + lane * CC + j;
            const int g  = blockBase + si;
            st[j] = (si >= bLo) && (si < bHi);
            K0[j] = 0.0f; K1[j] = K1u; K2[j] = K2u; K3[j] = K3u;
            if (g == 0)       { K0[j] = dt * BC * (2.0f * A * s1 + B);
                                K1[j] = dt * (3.0f * A * s0 - B);
                                K2[j] = 0.0f; }
            if (g == NXS - 1) { K1[j] = dt * (2.0f * A * s0 - B + A * s1);
                                K3[j] = 0.0f; }
        }
        unsigned off = (unsigned)(done * NXS + blockBase + a + lane * CC) * 8u;

        // comms prologue for first step of epoch
        float clS = __shfl_up(c[CC - 1], 1);
        float crS = __shfl_down(c[0], 1);
        float tt[CC]; float2 L[CC];
        #pragma unroll
        for (int j = 0; j < CC; ++j) {
            const float t2 = __builtin_amdgcn_fmed3f(
                fmaf(c[j], LUT_INV, LUT_BIAS), 0.0f, 4095.9f);
            tt[j] = t2; L[j] = slut[(int)t2];
        }

        // ---- inner loop: no barriers ----
        for (int s = 0; s < nst; ++s) {
            float nc[CC], nsk[CC];
            #pragma unroll
            for (int j = 0; j < CC; ++j) {
                const float cj  = c[j];
                const float pw  = fexp2(beta * flog2(fmaxf(cj, 1e-9f)));
                const float ret = fmaf(tt[j], L[j].x, L[j].y);
                const float cl  = (j == 0)      ? clS : c[j - 1];
                const float cr  = (j == CC - 1) ? crS : c[j + 1];
                float t_ = fmaf(K1[j], cj, K0[j]);
                t_ = fmaf(K2[j], cl, t_);
                t_ = fmaf(K3[j], cr, t_);
                float v = fmaf(ret, t_, cj);
                v = fmaf(-GAKD, pw, v);
                nc[j]  = fmaf(G, sk[j], v);
                nsk[j] = fmaf(S1c, sk[j], S2c * pw);
            }
            #pragma unroll
            for (int j = 0; j < CC; ++j) { c[j] = nc[j]; sk[j] = nsk[j]; }

            // comms for next step (latency hidden under this step's tail)
            clS = __shfl_up(c[CC - 1], 1);
            crS = __shfl_down(c[0], 1);
            #pragma unroll
            for (int j = 0; j < CC; ++j) {
                const float t2 = __builtin_amdgcn_fmed3f(
                    fmaf(c[j], LUT_INV, LUT_BIAS), 0.0f, 4095.9f);
                tt[j] = t2; L[j] = slut[(int)t2];
            }

            // trajectory stores (disjoint windows, fire-and-forget)
            #pragma unroll
            for (int j = 0; j < CC; ++j)
                if (st[j])
                    *reinterpret_cast<float2*>(outc + (off + 8u * j)) =
                        make_float2(c[j], sk[j]);
            off += (unsigned)(NXS * 8);
        }

        done += nst;
        if (done >= T) break;

        // ---- refill: write valid cores, re-tile slabs ----
        __syncthreads();
        {
            const int wLo = (w == 0 && leftA)  ? 0   : EPOCH;
            const int wHi = (w == 7 && rightA) ? 192 : 192 - EPOCH;
            #pragma unroll
            for (int j = 0; j < CC; ++j) {
                const int si = lane * CC + j;
                if (si >= wLo && si < wHi)
                    xbuf[a + si] = make_float2(c[j], sk[j]);
            }
        }
        __syncthreads();
        {
            const int vL2 = leftA ? 0 : done;
            const int vR2 = rightA ? SSPAN : SSPAN - done;
            a = vL2 + ((vR2 - vL2 - 192) * w) / 7;
            #pragma unroll
            for (int j = 0; j < CC; ++j) {
                const float2 u = xbuf[a + lane * CC + j];
                c[j] = u.x; sk[j] = u.y;
            }
        }
        __syncthreads();
    }
}

extern "C" void kernel_launch(void* const* d_in, const int* in_sizes, int n_in,
                              void* d_out, int out_size, void* d_ws, size_t ws_size,
                              hipStream_t stream)
{
    const float* u0 = (const float*)d_in[0];
    FinnPtrs P;
    P.tvec    = (const float*)d_in[1];
    const float* W0      = (const float*)d_in[2];
    const float* b0      = (const float*)d_in[3];
    const float* W1      = (const float*)d_in[4];
    const float* b1      = (const float*)d_in[5];
    const float* W2      = (const float*)d_in[6];
    const float* b2      = (const float*)d_in[7];
    const float* W3      = (const float*)d_in[8];
    const float* b3      = (const float*)d_in[9];
    const float* ret_fac = (const float*)d_in[10];
    P.Dp      = (const float*)d_in[11];
    P.stencil = (const float*)d_in[12];
    P.BCp     = (const float*)d_in[13];
    P.fp      = (const float*)d_in[14];
    P.kdp     = (const float*)d_in[15];
    P.betap   = (const float*)d_in[16];
    P.alphap  = (const float*)d_in[17];
    P.rhosp   = (const float*)d_in[18];
    P.nep     = (const float*)d_in[19];
    P.vep     = (const float*)d_in[20];
    P.dxp     = (const float*)d_in[21];

    float* out = (float*)d_out;
    float* lut = (float*)d_ws;          // (LUT_N+1)*4 B scratch
    const int T = in_sizes[1];          // 200

    hipLaunchKernelGGL(finn_lut, dim3((LUT_N + 1 + 255) / 256), dim3(256), 0,
                       stream, W0, b0, W1, b1, W2, b2, W3, b3, ret_fac, lut);

    // single launch for T <= MARG (=206); chunked fallback otherwise
    int done = 0;
    while (done < T) {
        const int h = (T - done < MARG) ? (T - done) : MARG;
        const float* src = (done == 0) ? u0 : out + (size_t)(done - 1) * NXS * 2;
        float* dst = out + (size_t)done * NXS * 2;
        hipLaunchKernelGGL(finn_sweep, dim3(NB), dim3(BTL), 0, stream,
                           src, dst, lut, P, h);
        done += h;
    }
}